// Round 1
// baseline (11626.775 us; speedup 1.0000x reference)
//
#include <hip/hip_runtime.h>

// Problem constants
// B=64, T=128, U=256, D_in=32, SKIP=4, dense: (64 x 32768) @ (32768 x 4096)

__device__ __forceinline__ float sigmoidf_(float x) {
    return 1.0f / (1.0f + __expf(-x));
}

// Pack a row-major (R x 1024) weight into float4 per (r, v): {W[r][v], W[r][256+v], W[r][512+v], W[r][768+v]}
__global__ __launch_bounds__(256) void pack_w4(
    const float* __restrict__ enc_rk, const float* __restrict__ dec_rk,
    const float* __restrict__ dec_k,  const float* __restrict__ enc_k,
    float4* __restrict__ rk4e, float4* __restrict__ rk4d,
    float4* __restrict__ dk4,  float4* __restrict__ ek4)
{
    int r = blockIdx.x, v = threadIdx.x;
    const float* src; float4* dst; int row;
    if (r < 256)      { src = enc_rk; dst = rk4e; row = r; }
    else if (r < 512) { src = dec_rk; dst = rk4d; row = r - 256; }
    else if (r < 768) { src = dec_k;  dst = dk4;  row = r - 512; }
    else              { src = enc_k;  dst = ek4;  row = r - 768; }
    const float* s = src + row * 1024;
    dst[row * 256 + v] = make_float4(s[v], s[256 + v], s[512 + v], s[768 + v]);
}

// One workgroup per batch element; 256 threads, thread v owns output column v.
// mode 0: enc (xsrc = X, computes xW on the fly, depth 32, adds bias)
// mode 1: dec (xsrc = packed xW float4, bias already included)
__global__ __launch_bounds__(256) void skip_lstm_rec(
    const float*  __restrict__ xsrc,
    const float4* __restrict__ ek4,
    const float*  __restrict__ bias,
    const float4* __restrict__ rk4,
    const float*  __restrict__ k2,
    const float*  __restrict__ bias2,
    const float*  __restrict__ s0p,
    float* __restrict__ out,
    int mode)
{
    const int b = blockIdx.x;
    const int v = threadIdx.x;
    __shared__ float4 h4[256];      // {i, f, c, o} of previous step, per u
    __shared__ float  pq[4][256];   // ring buffer of last 4 h outputs
    __shared__ float  xrow[32];

    h4[v] = make_float4(0.f, 0.f, 0.f, 0.f);
    pq[0][v] = 0.f; pq[1][v] = 0.f; pq[2][v] = 0.f; pq[3][v] = 0.f;
    float cst = 0.f;
    const float s0 = s0p[0];
    const float b2 = bias2[v];
    float4 bv = make_float4(0.f, 0.f, 0.f, 0.f);
    if (mode == 0) bv = make_float4(bias[v], bias[256 + v], bias[512 + v], bias[768 + v]);
    __syncthreads();

    for (int t = 0; t < 128; ++t) {
        const int slot = t & 3;
        float4 xa;
        if (mode == 0) {
            if (v < 32) xrow[v] = xsrc[(b * 129 * 128 + t) * 32 + v];  // X[b,0,t,v]
            __syncthreads();
            xa = bv;
            #pragma unroll
            for (int d = 0; d < 32; ++d) {
                float4 w = ek4[d * 256 + v];
                float xd = xrow[d];
                xa.x += xd * w.x; xa.y += xd * w.y; xa.z += xd * w.z; xa.w += xd * w.w;
            }
        } else {
            xa = reinterpret_cast<const float4*>(xsrc)[(b * 128 + t) * 256 + v];
        }

        float ai = 0.f, af = 0.f, ac = 0.f, ao = 0.f, as = 0.f;
        #pragma unroll 4
        for (int u = 0; u < 256; ++u) {
            float4 w  = rk4[u * 256 + v];
            float4 h  = h4[u];
            float  kw = k2[u * 256 + v];
            float  po = pq[slot][u];
            ai += h.x * w.x; af += h.y * w.y; ac += h.z * w.z; ao += h.w * w.w;
            as += po * kw;
        }

        float gi = sigmoidf_(xa.x + ai);
        float gf = sigmoidf_(xa.y + af);
        float cb = tanhf(xa.z + ac);
        cst = gf * cst + gi * cb;
        float go = sigmoidf_(xa.w + ao);
        float hh = go * tanhf(cst);
        float hs = sigmoidf_(as + b2);
        float hf = s0 * hh + (1.f - s0) * hs;

        __syncthreads();
        h4[v] = make_float4(gi, gf, cst, go);
        pq[slot][v] = hf;
        out[(b * 128 + t) * 256 + v] = hf;
        __syncthreads();
    }
}

// xW for decoder: (8192 x 256) @ (256 x 1024) + bias, written packed float4.
// 16 rows per block to amortize weight reads.
__global__ __launch_bounds__(256) void xw_gemm(
    const float*  __restrict__ SE,
    const float4* __restrict__ dk4,
    const float*  __restrict__ bias,
    float4* __restrict__ xWp)
{
    const int v = threadIdx.x;
    const int r0 = blockIdx.x * 16;
    __shared__ float se[16][256];
    #pragma unroll
    for (int rr = 0; rr < 16; ++rr)
        se[rr][v] = SE[(r0 + rr) * 256 + v];
    __syncthreads();

    float4 bv = make_float4(bias[v], bias[256 + v], bias[512 + v], bias[768 + v]);
    float4 acc[16];
    #pragma unroll
    for (int rr = 0; rr < 16; ++rr) acc[rr] = bv;

    for (int u = 0; u < 256; ++u) {
        float4 w = dk4[u * 256 + v];
        #pragma unroll
        for (int rr = 0; rr < 16; ++rr) {
            float s = se[rr][u];
            acc[rr].x += s * w.x; acc[rr].y += s * w.y;
            acc[rr].z += s * w.z; acc[rr].w += s * w.w;
        }
    }
    #pragma unroll
    for (int rr = 0; rr < 16; ++rr)
        xWp[(r0 + rr) * 256 + v] = acc[rr];
}

// Dense (RD @ dense_w + dense_b) fused with Z2 + final_b.
// Grid 256: jb = bx>>2 (64 cols each), bb = bx&3 (16 rows each). bb fast-varying for L3 reuse.
__global__ __launch_bounds__(256) void dense_out(
    const float* __restrict__ SD,   // (64 x 32768)
    const float* __restrict__ dw,   // (32768 x 4096)
    const float* __restrict__ db,   // (4096)
    const float* __restrict__ X,    // full X
    const float* __restrict__ fw,   // (128)
    const float* __restrict__ fbp,  // scalar
    float* __restrict__ out)        // (64*128*32)
{
    const int tid = threadIdx.x;
    const int jb = blockIdx.x >> 2;
    const int bb = blockIdx.x & 3;
    const int jq = tid & 15;
    const int br = tid >> 4;
    const int b  = bb * 16 + br;
    const int j0 = jb * 64 + jq * 4;

    __shared__ float rd[16][128];
    __shared__ float fwl[128];
    if (tid < 128) fwl[tid] = fw[tid];

    float4 acc = *reinterpret_cast<const float4*>(db + j0);

    for (int k0 = 0; k0 < 32768; k0 += 128) {
        __syncthreads();
        #pragma unroll
        for (int it = 0; it < 8; ++it) {
            int lin = it * 256 + tid;
            int row = lin >> 7, col = lin & 127;
            rd[row][col] = SD[(size_t)(bb * 16 + row) * 32768 + k0 + col];
        }
        __syncthreads();
        const float* wp = dw + (size_t)k0 * 4096 + j0;
        #pragma unroll 4
        for (int kk = 0; kk < 128; ++kk) {
            float4 w = *reinterpret_cast<const float4*>(wp + (size_t)kk * 4096);
            float s = rd[br][kk];
            acc.x += s * w.x; acc.y += s * w.y; acc.z += s * w.z; acc.w += s * w.w;
        }
    }

    // Z2: sum_s X[b, 1+i, s, m..m+3] * fw[s]  (i = j0/32, m = j0%32)
    const int i = j0 >> 5, m = j0 & 31;
    const float fb = fbp[0];
    const float* xp = X + ((size_t)(b * 129 + 1 + i) * 128) * 32 + m;
    #pragma unroll 4
    for (int s = 0; s < 128; ++s) {
        float4 xv = *reinterpret_cast<const float4*>(xp + s * 32);
        float w = fwl[s];
        acc.x += w * xv.x; acc.y += w * xv.y; acc.z += w * xv.z; acc.w += w * xv.w;
    }
    acc.x += fb; acc.y += fb; acc.z += fb; acc.w += fb;
    *reinterpret_cast<float4*>(out + (size_t)(b * 128 + i) * 32 + m) = acc;
}

extern "C" void kernel_launch(void* const* d_in, const int* in_sizes, int n_in,
                              void* d_out, int out_size, void* d_ws, size_t ws_size,
                              hipStream_t stream) {
    const float* X    = (const float*)d_in[0];
    const float* e_k  = (const float*)d_in[1];
    const float* e_rk = (const float*)d_in[2];
    const float* e_k2 = (const float*)d_in[3];
    const float* e_b  = (const float*)d_in[4];
    const float* e_b2 = (const float*)d_in[5];
    const float* e_s0 = (const float*)d_in[6];
    const float* d_k  = (const float*)d_in[7];
    const float* d_rk = (const float*)d_in[8];
    const float* d_k2 = (const float*)d_in[9];
    const float* d_b  = (const float*)d_in[10];
    const float* d_b2 = (const float*)d_in[11];
    const float* d_s0 = (const float*)d_in[12];
    const float* dw   = (const float*)d_in[13];
    const float* db   = (const float*)d_in[14];
    const float* fw   = (const float*)d_in[15];
    const float* fb   = (const float*)d_in[16];

    float* ws = (float*)d_ws;
    // workspace layout (floats): rk4e[256K] rk4d[256K] dk4[256K] ek4[32K pad to 256K] xWp[8M] SE[2M] SD[2M]
    float4* rk4e = (float4*)(ws);
    float4* rk4d = (float4*)(ws + 262144);
    float4* dk4  = (float4*)(ws + 524288);
    float4* ek4  = (float4*)(ws + 786432);
    float*  xWp  = ws + 1048576;    // 64*128*1024 = 8M floats
    float*  SE   = ws + 9437184;    // 64*128*256  = 2M floats
    float*  SD   = ws + 11534336;   // 2M floats

    hipLaunchKernelGGL(pack_w4, dim3(800), dim3(256), 0, stream,
                       e_rk, d_rk, d_k, e_k, rk4e, rk4d, dk4, ek4);
    hipLaunchKernelGGL(skip_lstm_rec, dim3(64), dim3(256), 0, stream,
                       X, ek4, e_b, rk4e, e_k2, e_b2, e_s0, SE, 0);
    hipLaunchKernelGGL(xw_gemm, dim3(512), dim3(256), 0, stream,
                       SE, dk4, d_b, (float4*)xWp);
    hipLaunchKernelGGL(skip_lstm_rec, dim3(64), dim3(256), 0, stream,
                       xWp, ek4, e_b, rk4d, d_k2, d_b2, d_s0, SD, 1);
    hipLaunchKernelGGL(dense_out, dim3(256), dim3(256), 0, stream,
                       SD, dw, db, X, fw, fb, (float*)d_out);
}

// Round 4
// 3153.381 us; speedup vs baseline: 3.6871x; 3.6871x over previous
//
#include <hip/hip_runtime.h>

// B=64, T=128, U=256, D_in=32, SKIP=4; dense: (64 x 32768) @ (32768 x 4096)

__device__ __forceinline__ float sigmoidf_(float x) {
    return 1.0f / (1.0f + __expf(-x));
}

// ---------------- weight packing (all fp32) ----------------
// rk4/dk4/ek4 per (u,v): float4{W[u][v], W[u][256+v], W[u][512+v], W[u][768+v]}
__global__ __launch_bounds__(256) void pack_w4(
    const float* __restrict__ enc_rk, const float* __restrict__ dec_rk,
    const float* __restrict__ dec_k,  const float* __restrict__ enc_k,
    float4* __restrict__ rk4e, float4* __restrict__ rk4d,
    float4* __restrict__ dk4,  float4* __restrict__ ek4)
{
    int r = blockIdx.x, v = threadIdx.x;
    const float* src; float4* dst; int row;
    if (r < 256)      { src = enc_rk; dst = rk4e; row = r; }
    else if (r < 512) { src = dec_rk; dst = rk4d; row = r - 256; }
    else if (r < 768) { src = dec_k;  dst = dk4;  row = r - 512; }
    else              { src = enc_k;  dst = ek4;  row = r - 768; }
    const float* s = src + row * 1024;
    dst[row * 256 + v] = make_float4(s[v], s[256 + v], s[512 + v], s[768 + v]);
}

// ---------------- xW GEMM (enc: K=32 rows gathered from X[:,0]; dec: K=256 from SE) ----------------
__global__ __launch_bounds__(256) void xw_gemm2(
    const float*  __restrict__ src,
    const float4* __restrict__ wk4,
    const float*  __restrict__ bias,
    float4* __restrict__ xWp,
    int K, int encmode)
{
    const int v = threadIdx.x;
    const int r0 = blockIdx.x * 16;
    __shared__ float se[16][256];

    if (encmode) {
        #pragma unroll
        for (int p = 0; p < 2; ++p) {
            int idx = p * 256 + v;
            int rr = idx >> 5, d = idx & 31;
            int R = r0 + rr, b = R >> 7, t = R & 127;
            // X[b, 0, t, d] = X[((b*129 + 0)*128 + t)*32 + d]
            se[rr][d] = src[((size_t)b * 129 * 128 + t) * 32 + d];
        }
    } else {
        #pragma unroll
        for (int rr = 0; rr < 16; ++rr)
            se[rr][v] = src[(size_t)(r0 + rr) * 256 + v];
    }
    __syncthreads();

    float4 bv = make_float4(bias[v], bias[256 + v], bias[512 + v], bias[768 + v]);
    float4 acc[16];
    #pragma unroll
    for (int rr = 0; rr < 16; ++rr) acc[rr] = bv;

    #pragma unroll 4
    for (int u = 0; u < K; ++u) {
        float4 w = wk4[u * 256 + v];
        #pragma unroll
        for (int rr = 0; rr < 16; ++rr) {
            float s = se[rr][u];
            acc[rr].x += s * w.x; acc[rr].y += s * w.y;
            acc[rr].z += s * w.z; acc[rr].w += s * w.w;
        }
    }
    #pragma unroll
    for (int rr = 0; rr < 16; ++rr)
        xWp[(size_t)(r0 + rr) * 256 + v] = acc[rr];
}

// ---------------- skip-LSTM recurrence: 1 block/batch, 1024 threads, u-split x4, fp32 weights ----------------
__global__ __launch_bounds__(1024) void rec2(
    const float4* __restrict__ xW,    // (B*128*256) float4, bias included
    const float4* __restrict__ rk4,   // (256*256) float4 gate weights
    const float*  __restrict__ k2,    // (256*256) fp32 skip weights
    const float*  __restrict__ bias2,
    const float*  __restrict__ s0p,
    float* __restrict__ out)          // (B*128*256)
{
    const int b   = blockIdx.x;
    const int tid = threadIdx.x;
    const int v   = tid & 255;
    const int c   = tid >> 8;   // 0..3 u-chunk

    __shared__ float4 h4[256];
    __shared__ float  pq[4][256];
    __shared__ float4 pA[4][256];
    __shared__ float  pS[4][256];

    if (tid < 256) {
        h4[v] = make_float4(0.f, 0.f, 0.f, 0.f);
        pq[0][v] = 0.f; pq[1][v] = 0.f; pq[2][v] = 0.f; pq[3][v] = 0.f;
    }
    float cst = 0.f;
    const float s0 = s0p[0];
    const float b2 = bias2[v];
    __syncthreads();

    const float4* wp = rk4 + (c * 64) * 256 + v;
    const float*  kp = k2  + (c * 64) * 256 + v;
    const int ubase = c * 64;

    for (int t = 0; t < 128; ++t) {
        const int slot = t & 3;
        float ai = 0.f, af = 0.f, acg = 0.f, ao = 0.f, as = 0.f;
        #pragma unroll 8
        for (int uu = 0; uu < 64; ++uu) {
            float4 w  = wp[uu * 256];
            float  kw = kp[uu * 256];
            float4 h  = h4[ubase + uu];
            float  po = pq[slot][ubase + uu];
            ai  += h.x * w.x;
            af  += h.y * w.y;
            acg += h.z * w.z;
            ao  += h.w * w.w;
            as  += po * kw;
        }
        pA[c][v] = make_float4(ai, af, acg, ao);
        pS[c][v] = as;
        __syncthreads();
        if (tid < 256) {
            float4 A0 = pA[0][v], A1 = pA[1][v], A2 = pA[2][v], A3 = pA[3][v];
            float  S  = pS[0][v] + pS[1][v] + pS[2][v] + pS[3][v];
            float4 xa = xW[(size_t)(b * 128 + t) * 256 + v];
            float gi = sigmoidf_(xa.x + A0.x + A1.x + A2.x + A3.x);
            float gf = sigmoidf_(xa.y + A0.y + A1.y + A2.y + A3.y);
            float cb = tanhf(xa.z + A0.z + A1.z + A2.z + A3.z);
            cst = gf * cst + gi * cb;
            float go = sigmoidf_(xa.w + A0.w + A1.w + A2.w + A3.w);
            float hh = go * tanhf(cst);
            float hs = sigmoidf_(S + b2);
            float hf = s0 * hh + (1.f - s0) * hs;
            h4[v] = make_float4(gi, gf, cst, go);
            pq[slot][v] = hf;
            out[(size_t)(b * 128 + t) * 256 + v] = hf;
        }
        __syncthreads();
    }
}

// ---------------- SD transpose: (64 x 32768) -> SDT (32768 x 64) ----------------
__global__ __launch_bounds__(256) void transp(const float* __restrict__ SD, float* __restrict__ SDT)
{
    const int k0 = blockIdx.x * 64;
    const int tid = threadIdx.x;
    __shared__ float t[64][65];
    #pragma unroll
    for (int i = 0; i < 4; ++i) {
        int idx = i * 256 + tid;
        int r = idx >> 4, c4 = (idx & 15) * 4;
        float4 x = *reinterpret_cast<const float4*>(SD + (size_t)r * 32768 + k0 + c4);
        t[r][c4] = x.x; t[r][c4 + 1] = x.y; t[r][c4 + 2] = x.z; t[r][c4 + 3] = x.w;
    }
    __syncthreads();
    #pragma unroll
    for (int i = 0; i < 4; ++i) {
        int idx = i * 256 + tid;
        int k = idx >> 4, r4 = (idx & 15) * 4;
        float4 o = make_float4(t[r4][k], t[r4 + 1][k], t[r4 + 2][k], t[r4 + 3][k]);
        *reinterpret_cast<float4*>(SDT + (size_t)(k0 + k) * 64 + r4) = o;
    }
}

// ---------------- dense split-K partials: grid = 64 col-tiles x 8 k-chunks ----------------
__global__ __launch_bounds__(256) void dense_partial(
    const float* __restrict__ SDT,   // (32768 x 64)
    const float* __restrict__ dw,    // (32768 x 4096)
    float* __restrict__ P)           // (8 x 64 x 4096)
{
    const int tid = threadIdx.x;
    const int ct = blockIdx.x & 63;
    const int kc = blockIdx.x >> 6;
    const int jq = tid & 15;
    const int rg = tid >> 4;
    const int j0 = ct * 64 + jq * 4;
    const int r0 = rg * 4;

    const float* sp = SDT + (size_t)kc * 4096 * 64 + r0;
    const float* wp = dw + (size_t)kc * 4096 * 4096 + j0;

    float4 a0 = make_float4(0.f,0.f,0.f,0.f), a1 = a0, a2 = a0, a3 = a0;
    #pragma unroll 8
    for (int kk = 0; kk < 4096; ++kk) {
        float4 s4 = *reinterpret_cast<const float4*>(sp + (size_t)kk * 64);
        float4 w4 = *reinterpret_cast<const float4*>(wp + (size_t)kk * 4096);
        a0.x += s4.x * w4.x; a0.y += s4.x * w4.y; a0.z += s4.x * w4.z; a0.w += s4.x * w4.w;
        a1.x += s4.y * w4.x; a1.y += s4.y * w4.y; a1.z += s4.y * w4.z; a1.w += s4.y * w4.w;
        a2.x += s4.z * w4.x; a2.y += s4.z * w4.y; a2.z += s4.z * w4.z; a2.w += s4.z * w4.w;
        a3.x += s4.w * w4.x; a3.y += s4.w * w4.y; a3.z += s4.w * w4.z; a3.w += s4.w * w4.w;
    }
    float* p0 = P + ((size_t)(kc * 64 + r0) * 4096) + j0;
    *reinterpret_cast<float4*>(p0)               = a0;
    *reinterpret_cast<float4*>(p0 + 4096)        = a1;
    *reinterpret_cast<float4*>(p0 + 2 * 4096)    = a2;
    *reinterpret_cast<float4*>(p0 + 3 * 4096)    = a3;
}

// ---------------- reduce partials + bias + Z2 ----------------
__global__ __launch_bounds__(256) void reduce_z2(
    const float* __restrict__ P,
    const float* __restrict__ db,
    const float* __restrict__ X,
    const float* __restrict__ fw,
    const float* __restrict__ fbp,
    float* __restrict__ out)
{
    const int o4 = blockIdx.x * 256 + threadIdx.x;   // 0..65535
    const int b  = o4 >> 10;
    const int j4 = o4 & 1023;
    const int j0 = j4 * 4;
    const int i  = j0 >> 5;
    const int m  = j0 & 31;

    float4 acc = *reinterpret_cast<const float4*>(db + j0);
    #pragma unroll
    for (int kc = 0; kc < 8; ++kc) {
        float4 p = *reinterpret_cast<const float4*>(P + (size_t)(kc * 64 + b) * 4096 + j0);
        acc.x += p.x; acc.y += p.y; acc.z += p.z; acc.w += p.w;
    }

    const float* xp = X + ((size_t)(b * 129 + 1 + i) * 128) * 32 + m;
    #pragma unroll 8
    for (int s = 0; s < 128; ++s) {
        float4 xv = *reinterpret_cast<const float4*>(xp + (size_t)s * 32);
        float w = fw[s];
        acc.x += w * xv.x; acc.y += w * xv.y; acc.z += w * xv.z; acc.w += w * xv.w;
    }
    const float fb = fbp[0];
    acc.x += fb; acc.y += fb; acc.z += fb; acc.w += fb;
    *reinterpret_cast<float4*>(out + (size_t)o4 * 4) = acc;
}

extern "C" void kernel_launch(void* const* d_in, const int* in_sizes, int n_in,
                              void* d_out, int out_size, void* d_ws, size_t ws_size,
                              hipStream_t stream) {
    const float* X    = (const float*)d_in[0];
    const float* e_k  = (const float*)d_in[1];
    const float* e_rk = (const float*)d_in[2];
    const float* e_k2 = (const float*)d_in[3];
    const float* e_b  = (const float*)d_in[4];
    const float* e_b2 = (const float*)d_in[5];
    const float* e_s0 = (const float*)d_in[6];
    const float* d_k  = (const float*)d_in[7];
    const float* d_rk = (const float*)d_in[8];
    const float* d_k2 = (const float*)d_in[9];
    const float* d_b  = (const float*)d_in[10];
    const float* d_b2 = (const float*)d_in[11];
    const float* d_s0 = (const float*)d_in[12];
    const float* dw   = (const float*)d_in[13];
    const float* db   = (const float*)d_in[14];
    const float* fw   = (const float*)d_in[15];
    const float* fb   = (const float*)d_in[16];

    float* ws = (float*)d_ws;
    // workspace layout (float offsets): rk4e[256K] rk4d[256K] dk4[256K] ek4[32K] | xW[8M] SE[2M] SD[2M]
    float4* rk4e = (float4*)(ws);
    float4* rk4d = (float4*)(ws + 262144);
    float4* dk4  = (float4*)(ws + 524288);
    float4* ek4  = (float4*)(ws + 786432);
    float*  xW   = ws + 1048576;    // 64*128*1024 = 8M floats; reused as P later
    float*  SE   = ws + 9437184;    // 2M floats; reused as SDT later
    float*  SD   = ws + 11534336;   // 2M floats

    float* P   = xW;   // 8*64*4096 = 2M f, xW dead by then
    float* SDT = SE;   // 32768*64 = 2M f, SE dead by then

    hipLaunchKernelGGL(pack_w4, dim3(800), dim3(256), 0, stream,
                       e_rk, d_rk, d_k, e_k, rk4e, rk4d, dk4, ek4);
    hipLaunchKernelGGL(xw_gemm2, dim3(512), dim3(256), 0, stream,
                       X, ek4, e_b, (float4*)xW, 32, 1);
    hipLaunchKernelGGL(rec2, dim3(64), dim3(1024), 0, stream,
                       (const float4*)xW, rk4e, e_k2, e_b2, e_s0, SE);
    hipLaunchKernelGGL(xw_gemm2, dim3(512), dim3(256), 0, stream,
                       SE, dk4, d_b, (float4*)xW, 256, 0);
    hipLaunchKernelGGL(rec2, dim3(64), dim3(1024), 0, stream,
                       (const float4*)xW, rk4d, d_k2, d_b2, d_s0, SD);
    hipLaunchKernelGGL(transp, dim3(512), dim3(256), 0, stream, SD, SDT);
    hipLaunchKernelGGL(dense_partial, dim3(512), dim3(256), 0, stream, SDT, dw, P);
    hipLaunchKernelGGL(reduce_z2, dim3(256), dim3(256), 0, stream,
                       P, db, X, fw, fb, (float*)d_out);
}